// Round 1
// baseline (349.614 us; speedup 1.0000x reference)
//
#include <hip/hip_runtime.h>

// Problem constants
#define BN_NODES 4096      // B*N = 8*512
#define KNN 16
#define C_POOL 256
#define G_DIM 128
#define IN_DIM 384         // C_POOL + G_DIM
#define L_DIM 512
#define OUT_STRIDE 1920    // 384 + 3*512

// d_out column offsets of x0..x3
#define X0_OFF 0
#define X1_OFF 384
#define X2_OFF 896
#define X3_OFF 1408

// ---------------------------------------------------------------------------
// Kernel 1: per-node geometry MLP + pooled copy -> x0 = d_out[:, 0:384]
// grid: 4096 blocks, 128 threads
// ---------------------------------------------------------------------------
__global__ __launch_bounds__(128) void node_feat_kernel(
    const float* __restrict__ rois, const float* __restrict__ pooled,
    const float* __restrict__ gW1, const float* __restrict__ gb1,
    const float* __restrict__ gW2, const float* __restrict__ gb2,
    float* __restrict__ out) {
  int n = blockIdx.x;
  int t = threadIdx.x;
  __shared__ float r[7];
  __shared__ float h1[G_DIM];
  if (t < 7) r[t] = rois[(size_t)n * 7 + t];
  __syncthreads();
  float acc = gb1[t];
#pragma unroll
  for (int i = 0; i < 7; i++) acc += r[i] * gW1[t * 7 + i];
  h1[t] = fmaxf(acc, 0.f);
  __syncthreads();
  float acc2 = gb2[t];
#pragma unroll 8
  for (int i = 0; i < G_DIM; i++) acc2 += h1[i] * gW2[t * G_DIM + i];
  float* orow = out + (size_t)n * OUT_STRIDE;
  orow[C_POOL + t] = fmaxf(acc2, 0.f);
  const float* prow = pooled + (size_t)n * C_POOL;
  orow[t] = prow[t];
  orow[G_DIM + t] = prow[G_DIM + t];
}

// ---------------------------------------------------------------------------
// Kernel 2: transpose fcW (512 x 2K) into Wt (K x 1024):
//   Wt[k][j] = (j<512) ? W[j][k] : W[j-512][K+k]
// ---------------------------------------------------------------------------
__global__ __launch_bounds__(256) void wtrans_kernel(
    const float* __restrict__ W, int K, float* __restrict__ Wt) {
  int idx = blockIdx.x * 256 + threadIdx.x;
  if (idx >= K * 1024) return;
  int k = idx >> 10;
  int j = idx & 1023;
  float v = (j < 512) ? W[(size_t)j * (2 * K) + k]
                      : W[(size_t)(j - 512) * (2 * K) + K + k];
  Wt[idx] = v;
}

// ---------------------------------------------------------------------------
// Kernel 3: fp32 tiled GEMM  PQ[4096 x 1024] = X[4096 x K] @ Wt[K x 1024]
// X has row stride ldx (reads from d_out). Tile: BM=128, BN=64, BK=16,
// 256 threads, 8x4 accum per thread.
// ---------------------------------------------------------------------------
#define GBM 128
#define GBN 64
#define GBK 16
__global__ __launch_bounds__(256) void gemm_kernel(
    const float* __restrict__ X, int ldx, int K,
    const float* __restrict__ Wt, float* __restrict__ PQ) {
  __shared__ float As[GBK][GBM + 1];
  __shared__ float Bs[GBK][GBN];
  const int bm = blockIdx.x;
  const int bn = blockIdx.y;
  const int tid = threadIdx.x;
  const int tx = tid & 15;   // 16 cols of 4
  const int ty = tid >> 4;   // 16 rows of 8
  float acc[8][4] = {};
  const float* Ablk = X + (size_t)(bm * GBM) * ldx;
  const float* Bblk = Wt + bn * GBN;
  for (int k0 = 0; k0 < K; k0 += GBK) {
#pragma unroll
    for (int r = 0; r < 8; r++) {
      int idx = tid + r * 256;
      int m = idx >> 4, kk = idx & 15;
      As[kk][m] = Ablk[(size_t)m * ldx + k0 + kk];
    }
#pragma unroll
    for (int r = 0; r < 4; r++) {
      int idx = tid + r * 256;
      int kk = idx >> 6, nn = idx & 63;
      Bs[kk][nn] = Bblk[(size_t)(k0 + kk) * 1024 + nn];
    }
    __syncthreads();
#pragma unroll
    for (int kk = 0; kk < GBK; kk++) {
      float a[8], b[4];
#pragma unroll
      for (int i = 0; i < 8; i++) a[i] = As[kk][ty * 8 + i];
#pragma unroll
      for (int j = 0; j < 4; j++) b[j] = Bs[kk][tx * 4 + j];
#pragma unroll
      for (int i = 0; i < 8; i++)
#pragma unroll
        for (int j = 0; j < 4; j++) acc[i][j] += a[i] * b[j];
    }
    __syncthreads();
  }
#pragma unroll
  for (int i = 0; i < 8; i++) {
    int m = bm * GBM + ty * 8 + i;
    float* row = PQ + (size_t)m * 1024 + bn * GBN + tx * 4;
#pragma unroll
    for (int j = 0; j < 4; j++) row[j] = acc[i][j];
  }
}

// ---------------------------------------------------------------------------
// Kernel 4: edge gather + max + relu.
//   x_new[n][c] = relu( max_k P[src[n*16+k]][c] + Q[n][c] - P[n][c] + b[c] )
// PQ row = 1024 floats = 256 float4 (P: first 128, Q: next 128).
// grid: 4096 blocks, 128 threads (float4 per thread).
// ---------------------------------------------------------------------------
__global__ __launch_bounds__(128) void edge_kernel(
    const float4* __restrict__ PQ, const int* __restrict__ src,
    const float* __restrict__ bias, float* __restrict__ out, int out_off) {
  int n = blockIdx.x;
  int t = threadIdx.x;
  __shared__ int s[KNN];
  if (t < KNN) s[t] = src[n * KNN + t];
  __syncthreads();
  const float4* row = PQ + (size_t)n * 256;
  float4 p = row[t];
  float4 q = row[128 + t];
  float4 bb = ((const float4*)bias)[t];
  float bx = q.x - p.x + bb.x;
  float by = q.y - p.y + bb.y;
  float bz = q.z - p.z + bb.z;
  float bw = q.w - p.w + bb.w;
  float mx = -1e30f, my = -1e30f, mz = -1e30f, mw = -1e30f;
#pragma unroll
  for (int k = 0; k < KNN; k++) {
    const float4 u = PQ[(size_t)s[k] * 256 + t];
    mx = fmaxf(mx, u.x);
    my = fmaxf(my, u.y);
    mz = fmaxf(mz, u.z);
    mw = fmaxf(mw, u.w);
  }
  float4 res;
  res.x = fmaxf(mx + bx, 0.f);
  res.y = fmaxf(my + by, 0.f);
  res.z = fmaxf(mz + bz, 0.f);
  res.w = fmaxf(mw + bw, 0.f);
  float* orow = out + (size_t)n * OUT_STRIDE + out_off;
  ((float4*)orow)[t] = res;
}

extern "C" void kernel_launch(void* const* d_in, const int* in_sizes, int n_in,
                              void* d_out, int out_size, void* d_ws,
                              size_t ws_size, hipStream_t stream) {
  const float* rois = (const float*)d_in[0];
  const float* pooled = (const float*)d_in[1];
  const int* edge_index = (const int*)d_in[2];
  const float* gW1 = (const float*)d_in[3];
  const float* gb1 = (const float*)d_in[4];
  const float* gW2 = (const float*)d_in[5];
  const float* gb2 = (const float*)d_in[6];
  const float* fcW[3] = {(const float*)d_in[7], (const float*)d_in[9],
                         (const float*)d_in[11]};
  const float* fcb[3] = {(const float*)d_in[8], (const float*)d_in[10],
                         (const float*)d_in[12]};
  float* out = (float*)d_out;

  const int* src = edge_index;  // first 65536 entries; dst[e] == e/16 by construction

  // workspace: PQ (4096*1024 f32 = 16 MB) | Wt (512*1024 f32 = 2 MB)
  float* PQ = (float*)d_ws;
  float* Wt = PQ + (size_t)BN_NODES * 1024;

  // x0
  node_feat_kernel<<<BN_NODES, 128, 0, stream>>>(rois, pooled, gW1, gb1, gW2,
                                                 gb2, out);

  const int in_off[3] = {X0_OFF, X1_OFF, X2_OFF};
  const int out_off[3] = {X1_OFF, X2_OFF, X3_OFF};
  const int Kdim[3] = {IN_DIM, L_DIM, L_DIM};

  for (int l = 0; l < 3; l++) {
    int K = Kdim[l];
    int nT = K * 1024;
    wtrans_kernel<<<(nT + 255) / 256, 256, 0, stream>>>(fcW[l], K, Wt);
    dim3 ggrid(BN_NODES / GBM, 1024 / GBN);
    gemm_kernel<<<ggrid, 256, 0, stream>>>(out + in_off[l], OUT_STRIDE, K, Wt,
                                           PQ);
    edge_kernel<<<BN_NODES, 128, 0, stream>>>((const float4*)PQ, src, fcb[l],
                                              out, out_off[l]);
  }
}

// Round 2
// 214.845 us; speedup vs baseline: 1.6273x; 1.6273x over previous
//
#include <hip/hip_runtime.h>
#include <hip/hip_bf16.h>

// Problem constants
#define BN_NODES 4096      // B*N = 8*512
#define KNN 16
#define C_POOL 256
#define G_DIM 128
#define IN_DIM 384         // C_POOL + G_DIM
#define L_DIM 512
#define OUT_STRIDE 1920    // 384 + 3*512

#define X0_OFF 0
#define X1_OFF 384
#define X2_OFF 896
#define X3_OFF 1408

typedef __attribute__((ext_vector_type(8))) __bf16 bf16x8;
typedef __attribute__((ext_vector_type(4))) float floatx4;

static __device__ __forceinline__ unsigned short f2bf(float v) {
  return __builtin_bit_cast(unsigned short, __float2bfloat16(v));
}

// ---------------------------------------------------------------------------
// Kernel 1: per-node geometry MLP + pooled copy -> x0 (fp32 in out, bf16 in Xb)
// grid: 4096 blocks, 128 threads
// ---------------------------------------------------------------------------
__global__ __launch_bounds__(128) void node_feat_kernel(
    const float* __restrict__ rois, const float* __restrict__ pooled,
    const float* __restrict__ gW1, const float* __restrict__ gb1,
    const float* __restrict__ gW2, const float* __restrict__ gb2,
    float* __restrict__ out, __hip_bfloat16* __restrict__ Xb) {
  int n = blockIdx.x;
  int t = threadIdx.x;
  __shared__ float r[7];
  __shared__ float h1[G_DIM];
  if (t < 7) r[t] = rois[(size_t)n * 7 + t];
  __syncthreads();
  float acc = gb1[t];
#pragma unroll
  for (int i = 0; i < 7; i++) acc += r[i] * gW1[t * 7 + i];
  h1[t] = fmaxf(acc, 0.f);
  __syncthreads();
  float acc2 = gb2[t];
#pragma unroll 8
  for (int i = 0; i < G_DIM; i++) acc2 += h1[i] * gW2[t * G_DIM + i];
  float g = fmaxf(acc2, 0.f);
  float* orow = out + (size_t)n * OUT_STRIDE;
  const float* prow = pooled + (size_t)n * C_POOL;
  float p0 = prow[t], p1 = prow[G_DIM + t];
  orow[t] = p0;
  orow[G_DIM + t] = p1;
  orow[C_POOL + t] = g;
  __hip_bfloat16* xrow = Xb + (size_t)n * IN_DIM;
  xrow[t] = __float2bfloat16(p0);
  xrow[G_DIM + t] = __float2bfloat16(p1);
  xrow[C_POOL + t] = __float2bfloat16(g);
}

// ---------------------------------------------------------------------------
// Kernel 2: convert fcW (512 x 2K fp32) into Wb (1024 x K bf16):
//   Wb[j][k] = (j<512) ? W[j][k] : W[j-512][K+k]
// grid: (K/128, 1024), 128 threads
// ---------------------------------------------------------------------------
__global__ __launch_bounds__(128) void wconv_kernel(
    const float* __restrict__ W, int K, __hip_bfloat16* __restrict__ Wb) {
  int k = blockIdx.x * 128 + threadIdx.x;
  int j = blockIdx.y;
  float v = (j < 512) ? W[(size_t)j * (2 * K) + k]
                      : W[(size_t)(j - 512) * (2 * K) + K + k];
  Wb[(size_t)j * K + k] = __float2bfloat16(v);
}

// ---------------------------------------------------------------------------
// Kernel 3: bf16 MFMA GEMM  PQ[4096 x 1024] = Xb[4096 x K] @ Wb[1024 x K]^T
// Tile 128x128, BK=32, 256 threads = 4 waves (2x2), 4x4 mfma tiles/wave.
// Staging: global_load_lds width 16 into row-major 128x32 bf16 tiles.
// ---------------------------------------------------------------------------
__global__ __launch_bounds__(256) void mfma_gemm_kernel(
    const ushort* __restrict__ Xb, const ushort* __restrict__ Wb, int K,
    float* __restrict__ PQ) {
  __shared__ ushort sA[128 * 32];
  __shared__ ushort sB[128 * 32];
  const int tid = threadIdx.x;
  const int lane = tid & 63;
  const int w = tid >> 6;        // wave 0..3
  const int wm = w >> 1;         // wave row (0..1)
  const int wn = w & 1;          // wave col (0..1)
  const int fr = lane & 15;      // m/n within 16-tile
  const int quad = lane >> 4;    // 0..3
  const int srow = lane >> 2;    // staging row within 16-row chunk
  const int scol = (lane & 3) * 8;  // staging col (bf16 elements)

  floatx4 acc[4][4];
#pragma unroll
  for (int i = 0; i < 4; i++)
#pragma unroll
    for (int j = 0; j < 4; j++) acc[i][j] = (floatx4){0.f, 0.f, 0.f, 0.f};

  const size_t aBase = (size_t)blockIdx.x * 128 + w * 32;
  const size_t bBase = (size_t)blockIdx.y * 128 + w * 32;

  for (int k0 = 0; k0 < K; k0 += 32) {
#pragma unroll
    for (int p = 0; p < 2; p++) {
      const ushort* ga = Xb + (aBase + p * 16 + srow) * K + (k0 + scol);
      const ushort* gb = Wb + (bBase + p * 16 + srow) * K + (k0 + scol);
      __builtin_amdgcn_global_load_lds(
          (const __attribute__((address_space(1))) void*)ga,
          (__attribute__((address_space(3))) void*)&sA[(w * 32 + p * 16) * 32],
          16, 0, 0);
      __builtin_amdgcn_global_load_lds(
          (const __attribute__((address_space(1))) void*)gb,
          (__attribute__((address_space(3))) void*)&sB[(w * 32 + p * 16) * 32],
          16, 0, 0);
    }
    __syncthreads();
    bf16x8 af[4], bfr[4];
#pragma unroll
    for (int i = 0; i < 4; i++)
      af[i] = *(const bf16x8*)&sA[(wm * 64 + i * 16 + fr) * 32 + quad * 8];
#pragma unroll
    for (int j = 0; j < 4; j++)
      bfr[j] = *(const bf16x8*)&sB[(wn * 64 + j * 16 + fr) * 32 + quad * 8];
#pragma unroll
    for (int i = 0; i < 4; i++)
#pragma unroll
      for (int j = 0; j < 4; j++)
        acc[i][j] = __builtin_amdgcn_mfma_f32_16x16x32_bf16(af[i], bfr[j],
                                                            acc[i][j], 0, 0, 0);
    __syncthreads();
  }

  const int rowB = blockIdx.x * 128 + wm * 64 + quad * 4;
  const int colB = blockIdx.y * 128 + wn * 64 + fr;
#pragma unroll
  for (int i = 0; i < 4; i++)
#pragma unroll
    for (int j = 0; j < 4; j++) {
      float* base = PQ + (size_t)(rowB + i * 16) * 1024 + colB + j * 16;
#pragma unroll
      for (int r = 0; r < 4; r++) base[(size_t)r * 1024] = acc[i][j][r];
    }
}

// ---------------------------------------------------------------------------
// Kernel 4: edge gather + max + relu; writes fp32 slice of out + bf16 Xb
//   x_new[n][c] = relu( max_k P[src[n*16+k]][c] + Q[n][c] - P[n][c] + b[c] )
// ---------------------------------------------------------------------------
__global__ __launch_bounds__(128) void edge_kernel(
    const float4* __restrict__ PQ, const int* __restrict__ src,
    const float* __restrict__ bias, float* __restrict__ out, int out_off,
    __hip_bfloat16* __restrict__ Xb) {
  int n = blockIdx.x;
  int t = threadIdx.x;
  __shared__ int s[KNN];
  if (t < KNN) s[t] = src[n * KNN + t];
  __syncthreads();
  const float4* row = PQ + (size_t)n * 256;
  float4 p = row[t];
  float4 q = row[128 + t];
  float4 bb = ((const float4*)bias)[t];
  float bx = q.x - p.x + bb.x;
  float by = q.y - p.y + bb.y;
  float bz = q.z - p.z + bb.z;
  float bw = q.w - p.w + bb.w;
  float mx = -1e30f, my = -1e30f, mz = -1e30f, mw = -1e30f;
#pragma unroll
  for (int k = 0; k < KNN; k++) {
    const float4 u = PQ[(size_t)s[k] * 256 + t];
    mx = fmaxf(mx, u.x);
    my = fmaxf(my, u.y);
    mz = fmaxf(mz, u.z);
    mw = fmaxf(mw, u.w);
  }
  float4 res;
  res.x = fmaxf(mx + bx, 0.f);
  res.y = fmaxf(my + by, 0.f);
  res.z = fmaxf(mz + bz, 0.f);
  res.w = fmaxf(mw + bw, 0.f);
  float* orow = out + (size_t)n * OUT_STRIDE + out_off;
  ((float4*)orow)[t] = res;
  ushort4 pk;
  pk.x = f2bf(res.x);
  pk.y = f2bf(res.y);
  pk.z = f2bf(res.z);
  pk.w = f2bf(res.w);
  ((ushort4*)(Xb + (size_t)n * L_DIM))[t] = pk;
}

extern "C" void kernel_launch(void* const* d_in, const int* in_sizes, int n_in,
                              void* d_out, int out_size, void* d_ws,
                              size_t ws_size, hipStream_t stream) {
  const float* rois = (const float*)d_in[0];
  const float* pooled = (const float*)d_in[1];
  const int* edge_index = (const int*)d_in[2];
  const float* gW1 = (const float*)d_in[3];
  const float* gb1 = (const float*)d_in[4];
  const float* gW2 = (const float*)d_in[5];
  const float* gb2 = (const float*)d_in[6];
  const float* fcW[3] = {(const float*)d_in[7], (const float*)d_in[9],
                         (const float*)d_in[11]};
  const float* fcb[3] = {(const float*)d_in[8], (const float*)d_in[10],
                         (const float*)d_in[12]};
  float* out = (float*)d_out;
  const int* src = edge_index;  // dst[e] == e/16 by construction

  // workspace layout:
  //   PQ : 4096*1024 fp32 = 16 MB
  //   Xb : 4096*512  bf16 =  4 MB
  //   Wb : 1024*512  bf16 =  1 MB
  float* PQ = (float*)d_ws;
  __hip_bfloat16* Xb = (__hip_bfloat16*)((char*)d_ws + (size_t)16 * 1024 * 1024);
  __hip_bfloat16* Wb = (__hip_bfloat16*)((char*)d_ws + (size_t)20 * 1024 * 1024);

  node_feat_kernel<<<BN_NODES, 128, 0, stream>>>(rois, pooled, gW1, gb1, gW2,
                                                 gb2, out, Xb);

  const int out_off[3] = {X1_OFF, X2_OFF, X3_OFF};
  const int Kdim[3] = {IN_DIM, L_DIM, L_DIM};

  for (int l = 0; l < 3; l++) {
    int K = Kdim[l];
    wconv_kernel<<<dim3(K / 128, 1024), 128, 0, stream>>>(fcW[l], K, Wb);
    mfma_gemm_kernel<<<dim3(32, 8), 256, 0, stream>>>(
        (const ushort*)Xb, (const ushort*)Wb, K, PQ);
    edge_kernel<<<BN_NODES, 128, 0, stream>>>((const float4*)PQ, src, fcb[l],
                                              out, out_off[l], Xb);
  }
}

// Round 3
// 190.592 us; speedup vs baseline: 1.8344x; 1.1272x over previous
//
#include <hip/hip_runtime.h>
#include <hip/hip_bf16.h>

// Problem constants
#define BN_NODES 4096      // B*N = 8*512
#define KNN 16
#define C_POOL 256
#define G_DIM 128
#define IN_DIM 384         // C_POOL + G_DIM
#define L_DIM 512
#define OUT_STRIDE 1920    // 384 + 3*512

#define X0_OFF 0
#define X1_OFF 384
#define X2_OFF 896
#define X3_OFF 1408

typedef __attribute__((ext_vector_type(8))) __bf16 bf16x8;
typedef __attribute__((ext_vector_type(4))) float floatx4;

static __device__ __forceinline__ ushort f2bf(float v) {
  return __builtin_bit_cast(ushort, __float2bfloat16(v));
}
static __device__ __forceinline__ float bf2f(ushort u) {
  return __builtin_bit_cast(float, ((unsigned)u) << 16);
}

// ---------------------------------------------------------------------------
// Kernel 1: per-node geometry MLP + pooled copy -> x0 (fp32 in out, bf16 Xb)
// grid: 4096 blocks, 128 threads
// ---------------------------------------------------------------------------
__global__ __launch_bounds__(128) void node_feat_kernel(
    const float* __restrict__ rois, const float* __restrict__ pooled,
    const float* __restrict__ gW1, const float* __restrict__ gb1,
    const float* __restrict__ gW2, const float* __restrict__ gb2,
    float* __restrict__ out, ushort* __restrict__ Xb) {
  int n = blockIdx.x;
  int t = threadIdx.x;
  __shared__ float r[7];
  __shared__ __align__(16) float h1[G_DIM];
  if (t < 7) r[t] = rois[(size_t)n * 7 + t];
  __syncthreads();
  float acc = gb1[t];
#pragma unroll
  for (int i = 0; i < 7; i++) acc += r[i] * gW1[t * 7 + i];
  h1[t] = fmaxf(acc, 0.f);
  __syncthreads();
  float acc2 = gb2[t];
  const float4* w4 = (const float4*)(gW2 + (size_t)t * G_DIM);
  const float4* h4 = (const float4*)h1;
#pragma unroll 8
  for (int i = 0; i < G_DIM / 4; i++) {
    float4 wv = w4[i];
    float4 hv = h4[i];
    acc2 += wv.x * hv.x + wv.y * hv.y + wv.z * hv.z + wv.w * hv.w;
  }
  float g = fmaxf(acc2, 0.f);
  float* orow = out + (size_t)n * OUT_STRIDE;
  const float* prow = pooled + (size_t)n * C_POOL;
  float p0 = prow[t], p1 = prow[G_DIM + t];
  orow[t] = p0;
  orow[G_DIM + t] = p1;
  orow[C_POOL + t] = g;
  ushort* xrow = Xb + (size_t)n * IN_DIM;
  xrow[t] = f2bf(p0);
  xrow[G_DIM + t] = f2bf(p1);
  xrow[C_POOL + t] = f2bf(g);
}

// ---------------------------------------------------------------------------
// Kernel 2: convert all three fcW (512 x 2K fp32) into Wb_l (1024 x K bf16):
//   Wb[j][k] = (j<512) ? W[j][k] : W[j-512][K+k]
// grid: (4, 1024, 3), 128 threads
// ---------------------------------------------------------------------------
__global__ __launch_bounds__(128) void wconv_all_kernel(
    const float* __restrict__ W0, const float* __restrict__ W1,
    const float* __restrict__ W2, ushort* __restrict__ Wb0,
    ushort* __restrict__ Wb1, ushort* __restrict__ Wb2) {
  int l = blockIdx.z;
  int j = blockIdx.y;
  int k = blockIdx.x * 128 + threadIdx.x;
  int K = (l == 0) ? IN_DIM : L_DIM;
  if (k >= K) return;
  const float* W = (l == 0) ? W0 : (l == 1) ? W1 : W2;
  ushort* Wb = (l == 0) ? Wb0 : (l == 1) ? Wb1 : Wb2;
  float v = (j < 512) ? W[(size_t)j * (2 * K) + k]
                      : W[(size_t)(j - 512) * (2 * K) + K + k];
  Wb[(size_t)j * K + k] = f2bf(v);
}

// ---------------------------------------------------------------------------
// Kernel 3: bf16 MFMA GEMM  PQb[4096 x 1024] = Xb[4096 x K] @ Wb[1024 x K]^T
// Tile 128x64 (MxN), BK=32, 256 threads = 4 waves (2x2); wave = 64x32
// (4x2 mfma tiles). grid (32,16) = 512 blocks = 2 blocks/CU.
// ---------------------------------------------------------------------------
__global__ __launch_bounds__(256) void mfma_gemm_kernel(
    const ushort* __restrict__ Xb, const ushort* __restrict__ Wb, int K,
    ushort* __restrict__ PQb) {
  __shared__ ushort sA[128 * 32];   // 8 KB
  __shared__ ushort sB[64 * 32];    // 4 KB
  const int tid = threadIdx.x;
  const int lane = tid & 63;
  const int w = tid >> 6;        // wave 0..3
  const int wm = w >> 1;         // wave row (0..1) -> 64 rows
  const int wn = w & 1;          // wave col (0..1) -> 32 cols
  const int fr = lane & 15;
  const int quad = lane >> 4;
  const int srow = lane >> 2;       // 16 rows per staging instr
  const int scol = (lane & 3) * 8;  // 8 bf16 = 16 B per lane

  floatx4 acc[4][2];
#pragma unroll
  for (int i = 0; i < 4; i++)
#pragma unroll
    for (int j = 0; j < 2; j++) acc[i][j] = (floatx4){0.f, 0.f, 0.f, 0.f};

  const size_t aBase = (size_t)blockIdx.x * 128 + w * 32;
  const size_t bBase = (size_t)blockIdx.y * 64 + w * 16;

  for (int k0 = 0; k0 < K; k0 += 32) {
#pragma unroll
    for (int p = 0; p < 2; p++) {
      const ushort* ga = Xb + (aBase + p * 16 + srow) * K + (k0 + scol);
      __builtin_amdgcn_global_load_lds(
          (const __attribute__((address_space(1))) void*)ga,
          (__attribute__((address_space(3))) void*)&sA[(w * 32 + p * 16) * 32],
          16, 0, 0);
    }
    {
      const ushort* gb = Wb + (bBase + srow) * K + (k0 + scol);
      __builtin_amdgcn_global_load_lds(
          (const __attribute__((address_space(1))) void*)gb,
          (__attribute__((address_space(3))) void*)&sB[(w * 16) * 32],
          16, 0, 0);
    }
    __syncthreads();
    bf16x8 af[4], bfr[2];
#pragma unroll
    for (int i = 0; i < 4; i++)
      af[i] = *(const bf16x8*)&sA[(wm * 64 + i * 16 + fr) * 32 + quad * 8];
#pragma unroll
    for (int j = 0; j < 2; j++)
      bfr[j] = *(const bf16x8*)&sB[(wn * 32 + j * 16 + fr) * 32 + quad * 8];
#pragma unroll
    for (int i = 0; i < 4; i++)
#pragma unroll
      for (int j = 0; j < 2; j++)
        acc[i][j] = __builtin_amdgcn_mfma_f32_16x16x32_bf16(af[i], bfr[j],
                                                            acc[i][j], 0, 0, 0);
    __syncthreads();
  }

  const int rowB = blockIdx.x * 128 + wm * 64 + quad * 4;
  const int colB = blockIdx.y * 64 + wn * 32 + fr;
#pragma unroll
  for (int i = 0; i < 4; i++)
#pragma unroll
    for (int j = 0; j < 2; j++)
#pragma unroll
      for (int r = 0; r < 4; r++)
        PQb[(size_t)(rowB + i * 16 + r) * 1024 + colB + j * 16] =
            f2bf(acc[i][j][r]);
}

// ---------------------------------------------------------------------------
// Kernel 4: edge gather + max + relu (bf16 PQ); writes fp32 out slice + Xb
//   x_new[n][c] = relu( max_k P[src[n*16+k]][c] + Q[n][c] - P[n][c] + b[c] )
// grid: 4096 blocks, 128 threads (4 channels/thread)
// ---------------------------------------------------------------------------
__global__ __launch_bounds__(128) void edge_kernel(
    const ushort* __restrict__ PQb, const int* __restrict__ src,
    const float* __restrict__ bias, float* __restrict__ out, int out_off,
    ushort* __restrict__ Xb) {
  int n = blockIdx.x;
  int t = threadIdx.x;
  __shared__ int s[KNN];
  if (t < KNN) s[t] = src[n * KNN + t];
  __syncthreads();
  const ushort* row = PQb + (size_t)n * 1024;
  ushort4 pu = *(const ushort4*)(row + t * 4);
  ushort4 qu = *(const ushort4*)(row + 512 + t * 4);
  float4 bb = ((const float4*)bias)[t];
  float bx = bf2f(qu.x) - bf2f(pu.x) + bb.x;
  float by = bf2f(qu.y) - bf2f(pu.y) + bb.y;
  float bz = bf2f(qu.z) - bf2f(pu.z) + bb.z;
  float bw = bf2f(qu.w) - bf2f(pu.w) + bb.w;
  float mx = -1e30f, my = -1e30f, mz = -1e30f, mw = -1e30f;
#pragma unroll
  for (int k = 0; k < KNN; k++) {
    ushort4 u = *(const ushort4*)(PQb + (size_t)s[k] * 1024 + t * 4);
    mx = fmaxf(mx, bf2f(u.x));
    my = fmaxf(my, bf2f(u.y));
    mz = fmaxf(mz, bf2f(u.z));
    mw = fmaxf(mw, bf2f(u.w));
  }
  float4 res;
  res.x = fmaxf(mx + bx, 0.f);
  res.y = fmaxf(my + by, 0.f);
  res.z = fmaxf(mz + bz, 0.f);
  res.w = fmaxf(mw + bw, 0.f);
  float* orow = out + (size_t)n * OUT_STRIDE + out_off;
  ((float4*)orow)[t] = res;
  ushort4 pk;
  pk.x = f2bf(res.x);
  pk.y = f2bf(res.y);
  pk.z = f2bf(res.z);
  pk.w = f2bf(res.w);
  ((ushort4*)(Xb + (size_t)n * L_DIM))[t] = pk;
}

extern "C" void kernel_launch(void* const* d_in, const int* in_sizes, int n_in,
                              void* d_out, int out_size, void* d_ws,
                              size_t ws_size, hipStream_t stream) {
  const float* rois = (const float*)d_in[0];
  const float* pooled = (const float*)d_in[1];
  const int* edge_index = (const int*)d_in[2];
  const float* gW1 = (const float*)d_in[3];
  const float* gb1 = (const float*)d_in[4];
  const float* gW2 = (const float*)d_in[5];
  const float* gb2 = (const float*)d_in[6];
  const float* fcW[3] = {(const float*)d_in[7], (const float*)d_in[9],
                         (const float*)d_in[11]};
  const float* fcb[3] = {(const float*)d_in[8], (const float*)d_in[10],
                         (const float*)d_in[12]};
  float* out = (float*)d_out;
  const int* src = edge_index;  // dst[e] == e/16 by construction

  // workspace layout (bytes):
  //   PQb : 4096*1024 bf16 = 8 MB   @ 0
  //   Xb  : 4096*512  bf16 = 4 MB   @ 8 MB
  //   Wb0 : 1024*384  bf16          @ 12 MB
  //   Wb1 : 1024*512  bf16          @ 13 MB
  //   Wb2 : 1024*512  bf16          @ 14 MB
  char* ws = (char*)d_ws;
  ushort* PQb = (ushort*)ws;
  ushort* Xb = (ushort*)(ws + (size_t)8 * 1024 * 1024);
  ushort* Wb[3] = {(ushort*)(ws + (size_t)12 * 1024 * 1024),
                   (ushort*)(ws + (size_t)13 * 1024 * 1024),
                   (ushort*)(ws + (size_t)14 * 1024 * 1024)};

  wconv_all_kernel<<<dim3(4, 1024, 3), 128, 0, stream>>>(
      fcW[0], fcW[1], fcW[2], Wb[0], Wb[1], Wb[2]);
  node_feat_kernel<<<BN_NODES, 128, 0, stream>>>(rois, pooled, gW1, gb1, gW2,
                                                 gb2, out, Xb);

  const int out_off[3] = {X1_OFF, X2_OFF, X3_OFF};
  const int Kdim[3] = {IN_DIM, L_DIM, L_DIM};

  for (int l = 0; l < 3; l++) {
    mfma_gemm_kernel<<<dim3(32, 16), 256, 0, stream>>>(Xb, Wb[l], Kdim[l],
                                                       PQb);
    edge_kernel<<<BN_NODES, 128, 0, stream>>>(PQb, src, fcb[l], out,
                                              out_off[l], Xb);
  }
}

// Round 4
// 177.552 us; speedup vs baseline: 1.9691x; 1.0734x over previous
//
#include <hip/hip_runtime.h>
#include <hip/hip_bf16.h>

// Problem constants
#define BN_NODES 4096      // B*N = 8*512
#define KNN 16
#define C_POOL 256
#define G_DIM 128
#define IN_DIM 384         // C_POOL + G_DIM
#define L_DIM 512
#define OUT_STRIDE 1920    // 384 + 3*512

#define X0_OFF 0
#define X1_OFF 384
#define X2_OFF 896
#define X3_OFF 1408

typedef __attribute__((ext_vector_type(8))) __bf16 bf16x8;
typedef __attribute__((ext_vector_type(4))) float floatx4;

static __device__ __forceinline__ ushort f2bf(float v) {
  return __builtin_bit_cast(ushort, __float2bfloat16(v));
}
static __device__ __forceinline__ float bf2f(ushort u) {
  return __builtin_bit_cast(float, ((unsigned)u) << 16);
}

// ---------------------------------------------------------------------------
// Kernel 1: per-node geometry MLP + pooled copy -> x0 (fp32 out slice + bf16 Xb)
// grid: 512 blocks x 256 threads; block handles 8 nodes.
// thread = (channel c = t&127, node-half nh = t>>7); gW2 read once per block
// (64 KB x 512 blocks = 32 MB L2 traffic vs 256 MB before).
// ---------------------------------------------------------------------------
__global__ __launch_bounds__(256) void node_feat_kernel(
    const float* __restrict__ rois, const float* __restrict__ pooled,
    const float* __restrict__ gW1, const float* __restrict__ gb1,
    const float* __restrict__ gW2, const float* __restrict__ gb2,
    float* __restrict__ out, ushort* __restrict__ Xb) {
  const int nb = blockIdx.x * 8;  // first node of this block
  const int t = threadIdx.x;
  const int c = t & 127;          // channel
  const int nh = t >> 7;          // node half (0: nodes 0-3, 1: nodes 4-7)
  __shared__ float rs[8 * 7];
  __shared__ __align__(16) float h1[8][G_DIM];
  if (t < 56) rs[t] = rois[(size_t)nb * 7 + t];
  __syncthreads();
  // phase 1: h1[n][c] = relu(gb1[c] + rois[n] . gW1[c])
  {
    float w1[7];
#pragma unroll
    for (int i = 0; i < 7; i++) w1[i] = gW1[c * 7 + i];
    float b1 = gb1[c];
#pragma unroll
    for (int n = nh * 4; n < nh * 4 + 4; n++) {
      float a = b1;
#pragma unroll
      for (int i = 0; i < 7; i++) a += rs[n * 7 + i] * w1[i];
      h1[n][c] = fmaxf(a, 0.f);
    }
  }
  __syncthreads();
  // phase 2: g[n][c] = relu(gb2[c] + h1[n] . gW2[c]) for 4 nodes
  float acc[4];
  {
    float b2 = gb2[c];
#pragma unroll
    for (int n = 0; n < 4; n++) acc[n] = b2;
    const float4* w4 = (const float4*)(gW2 + (size_t)c * G_DIM);
#pragma unroll 4
    for (int kc = 0; kc < G_DIM / 4; kc++) {
      float4 wv = w4[kc];
#pragma unroll
      for (int n = 0; n < 4; n++) {
        float4 hv = ((const float4*)h1[nh * 4 + n])[kc];
        acc[n] += wv.x * hv.x + wv.y * hv.y + wv.z * hv.z + wv.w * hv.w;
      }
    }
  }
#pragma unroll
  for (int n = 0; n < 4; n++) {
    int node = nb + nh * 4 + n;
    float g = fmaxf(acc[n], 0.f);
    const float* prow = pooled + (size_t)node * C_POOL;
    float p0 = prow[c], p1 = prow[G_DIM + c];
    float* orow = out + (size_t)node * OUT_STRIDE;
    orow[c] = p0;
    orow[G_DIM + c] = p1;
    orow[C_POOL + c] = g;
    ushort* xrow = Xb + (size_t)node * IN_DIM;
    xrow[c] = f2bf(p0);
    xrow[G_DIM + c] = f2bf(p1);
    xrow[C_POOL + c] = f2bf(g);
  }
}

// ---------------------------------------------------------------------------
// Kernel 2: convert all three fcW (512 x 2K fp32) into Wb_l (1024 x K bf16):
//   Wb[j][k] = (j<512) ? W[j][k] : W[j-512][K+k]
// grid: (4, 1024, 3), 128 threads
// ---------------------------------------------------------------------------
__global__ __launch_bounds__(128) void wconv_all_kernel(
    const float* __restrict__ W0, const float* __restrict__ W1,
    const float* __restrict__ W2, ushort* __restrict__ Wb0,
    ushort* __restrict__ Wb1, ushort* __restrict__ Wb2) {
  int l = blockIdx.z;
  int j = blockIdx.y;
  int k = blockIdx.x * 128 + threadIdx.x;
  int K = (l == 0) ? IN_DIM : L_DIM;
  if (k >= K) return;
  const float* W = (l == 0) ? W0 : (l == 1) ? W1 : W2;
  ushort* Wb = (l == 0) ? Wb0 : (l == 1) ? Wb1 : Wb2;
  float v = (j < 512) ? W[(size_t)j * (2 * K) + k]
                      : W[(size_t)(j - 512) * (2 * K) + K + k];
  Wb[(size_t)j * K + k] = f2bf(v);
}

// ---------------------------------------------------------------------------
// Kernel 3: bf16 MFMA GEMM  PQb[4096 x 1024] = Xb[4096 x K] @ Wb[1024 x K]^T
// Tile 128x64, BK=64, 256 threads = 4 waves (2x2), wave = 64x32.
// LDS stored in MFMA FRAGMENT ORDER: each 16x32 tile is its 64 lane-fragments
// contiguous (1 KB/tile) -> ds_read_b128 at tile_base + lane*16 is
// conflict-free (vs 8-way conflicts of row-major). global_load_lds per-lane
// source addresses implement the gather; LDS dest = base + lane*16 as required.
//   A tiles: t = ks*8 + rt  (rt = row-tile 0..7, ks = k-step 0..1)
//   B tiles: t = ks*4 + ct  (ct = col-tile 0..3)
// Fragment map (16x16x32): lane l holds [m = l&15][k = (l>>4)*8 + 0..7].
// ---------------------------------------------------------------------------
__global__ __launch_bounds__(256) void mfma_gemm_kernel(
    const ushort* __restrict__ Xb, const ushort* __restrict__ Wb, int K,
    ushort* __restrict__ PQb) {
  __shared__ ushort sA[128 * 64];  // 16 KB, 16 tiles
  __shared__ ushort sB[64 * 64];   // 8 KB, 8 tiles
  const int tid = threadIdx.x;
  const int lane = tid & 63;
  const int w = tid >> 6;
  const int wm = w >> 1, wn = w & 1;
  const int fr = lane & 15;   // row within tile
  const int kc = lane >> 4;   // k-chunk (x8 bf16)
  const int bm = blockIdx.x, bn = blockIdx.y;

  floatx4 acc[4][2];
#pragma unroll
  for (int i = 0; i < 4; i++)
#pragma unroll
    for (int j = 0; j < 2; j++) acc[i][j] = (floatx4){0.f, 0.f, 0.f, 0.f};

  for (int k0 = 0; k0 < K; k0 += 64) {
#pragma unroll
    for (int r = 0; r < 4; r++) {
      int t = w + r * 4;       // wave-uniform tile index
      int rt = t & 7, ks = t >> 3;
      const ushort* ga =
          Xb + (size_t)(bm * 128 + rt * 16 + fr) * K + k0 + ks * 32 + kc * 8;
      __builtin_amdgcn_global_load_lds(
          (const __attribute__((address_space(1))) void*)ga,
          (__attribute__((address_space(3))) void*)&sA[t * 512 + lane * 8], 16,
          0, 0);
    }
#pragma unroll
    for (int r = 0; r < 2; r++) {
      int t = w + r * 4;
      int ct = t & 3, ks = t >> 2;
      const ushort* gb =
          Wb + (size_t)(bn * 64 + ct * 16 + fr) * K + k0 + ks * 32 + kc * 8;
      __builtin_amdgcn_global_load_lds(
          (const __attribute__((address_space(1))) void*)gb,
          (__attribute__((address_space(3))) void*)&sB[t * 512 + lane * 8], 16,
          0, 0);
    }
    __syncthreads();
#pragma unroll
    for (int ks = 0; ks < 2; ks++) {
      bf16x8 af[4], bf[2];
#pragma unroll
      for (int i = 0; i < 4; i++)
        af[i] = *(const bf16x8*)&sA[(ks * 8 + wm * 4 + i) * 512 + lane * 8];
#pragma unroll
      for (int j = 0; j < 2; j++)
        bf[j] = *(const bf16x8*)&sB[(ks * 4 + wn * 2 + j) * 512 + lane * 8];
#pragma unroll
      for (int i = 0; i < 4; i++)
#pragma unroll
        for (int j = 0; j < 2; j++)
          acc[i][j] = __builtin_amdgcn_mfma_f32_16x16x32_bf16(af[i], bf[j],
                                                              acc[i][j], 0, 0,
                                                              0);
    }
    __syncthreads();
  }

  // C/D layout: col = lane&15 (fr), row = (lane>>4)*4 + reg  (m89-verified)
  const int rowB = bm * 128 + wm * 64 + kc * 4;
  const int colB = bn * 64 + wn * 32 + fr;
#pragma unroll
  for (int i = 0; i < 4; i++)
#pragma unroll
    for (int j = 0; j < 2; j++)
#pragma unroll
      for (int r = 0; r < 4; r++)
        PQb[(size_t)(rowB + i * 16 + r) * 1024 + colB + j * 16] =
            f2bf(acc[i][j][r]);
}

// ---------------------------------------------------------------------------
// Kernel 4: edge gather + max + relu (bf16 PQ); writes fp32 out slice + Xb
//   x_new[n][c] = relu( max_k P[src[n*16+k]][c] + Q[n][c] - P[n][c] + b[c] )
// grid: 4096 blocks, 128 threads (4 channels/thread)
// ---------------------------------------------------------------------------
__global__ __launch_bounds__(128) void edge_kernel(
    const ushort* __restrict__ PQb, const int* __restrict__ src,
    const float* __restrict__ bias, float* __restrict__ out, int out_off,
    ushort* __restrict__ Xb) {
  int n = blockIdx.x;
  int t = threadIdx.x;
  __shared__ int s[KNN];
  if (t < KNN) s[t] = src[n * KNN + t];
  __syncthreads();
  const ushort* row = PQb + (size_t)n * 1024;
  ushort4 pu = *(const ushort4*)(row + t * 4);
  ushort4 qu = *(const ushort4*)(row + 512 + t * 4);
  float4 bb = ((const float4*)bias)[t];
  float bx = bf2f(qu.x) - bf2f(pu.x) + bb.x;
  float by = bf2f(qu.y) - bf2f(pu.y) + bb.y;
  float bz = bf2f(qu.z) - bf2f(pu.z) + bb.z;
  float bw = bf2f(qu.w) - bf2f(pu.w) + bb.w;
  float mx = -1e30f, my = -1e30f, mz = -1e30f, mw = -1e30f;
#pragma unroll
  for (int k = 0; k < KNN; k++) {
    ushort4 u = *(const ushort4*)(PQb + (size_t)s[k] * 1024 + t * 4);
    mx = fmaxf(mx, bf2f(u.x));
    my = fmaxf(my, bf2f(u.y));
    mz = fmaxf(mz, bf2f(u.z));
    mw = fmaxf(mw, bf2f(u.w));
  }
  float4 res;
  res.x = fmaxf(mx + bx, 0.f);
  res.y = fmaxf(my + by, 0.f);
  res.z = fmaxf(mz + bz, 0.f);
  res.w = fmaxf(mw + bw, 0.f);
  float* orow = out + (size_t)n * OUT_STRIDE + out_off;
  ((float4*)orow)[t] = res;
  ushort4 pk;
  pk.x = f2bf(res.x);
  pk.y = f2bf(res.y);
  pk.z = f2bf(res.z);
  pk.w = f2bf(res.w);
  ((ushort4*)(Xb + (size_t)n * L_DIM))[t] = pk;
}

extern "C" void kernel_launch(void* const* d_in, const int* in_sizes, int n_in,
                              void* d_out, int out_size, void* d_ws,
                              size_t ws_size, hipStream_t stream) {
  const float* rois = (const float*)d_in[0];
  const float* pooled = (const float*)d_in[1];
  const int* edge_index = (const int*)d_in[2];
  const float* gW1 = (const float*)d_in[3];
  const float* gb1 = (const float*)d_in[4];
  const float* gW2 = (const float*)d_in[5];
  const float* gb2 = (const float*)d_in[6];
  const float* fcW[3] = {(const float*)d_in[7], (const float*)d_in[9],
                         (const float*)d_in[11]};
  const float* fcb[3] = {(const float*)d_in[8], (const float*)d_in[10],
                         (const float*)d_in[12]};
  float* out = (float*)d_out;
  const int* src = edge_index;  // dst[e] == e/16 by construction

  // workspace layout (bytes):
  //   PQb : 4096*1024 bf16 = 8 MB   @ 0
  //   Xb  : 4096*512  bf16 = 4 MB   @ 8 MB
  //   Wb0 : 1024*384  bf16          @ 12 MB
  //   Wb1 : 1024*512  bf16          @ 13 MB
  //   Wb2 : 1024*512  bf16          @ 14 MB
  char* ws = (char*)d_ws;
  ushort* PQb = (ushort*)ws;
  ushort* Xb = (ushort*)(ws + (size_t)8 * 1024 * 1024);
  ushort* Wb[3] = {(ushort*)(ws + (size_t)12 * 1024 * 1024),
                   (ushort*)(ws + (size_t)13 * 1024 * 1024),
                   (ushort*)(ws + (size_t)14 * 1024 * 1024)};

  wconv_all_kernel<<<dim3(4, 1024, 3), 128, 0, stream>>>(
      fcW[0], fcW[1], fcW[2], Wb[0], Wb[1], Wb[2]);
  node_feat_kernel<<<BN_NODES / 8, 256, 0, stream>>>(rois, pooled, gW1, gb1,
                                                     gW2, gb2, out, Xb);

  const int out_off[3] = {X1_OFF, X2_OFF, X3_OFF};
  const int Kdim[3] = {IN_DIM, L_DIM, L_DIM};

  for (int l = 0; l < 3; l++) {
    mfma_gemm_kernel<<<dim3(32, 16), 256, 0, stream>>>(Xb, Wb[l], Kdim[l],
                                                       PQb);
    edge_kernel<<<BN_NODES, 128, 0, stream>>>(PQb, src, fcb[l], out,
                                              out_off[l], Xb);
  }
}